// Round 17
// baseline (91.810 us; speedup 1.0000x reference)
//
#include <hip/hip_runtime.h>
#include <hip/hip_bf16.h>

#define F_DIM 256
#define N_DIM 128
#define B_DIM 4096

typedef float f32x2v __attribute__((ext_vector_type(2)));
typedef float f32x4v __attribute__((ext_vector_type(4)));
typedef float f32x16v __attribute__((ext_vector_type(16)));
typedef short s16x8 __attribute__((ext_vector_type(8)));
typedef unsigned int u32x4v __attribute__((ext_vector_type(4)));

// zero-cost VGPR pin (r7 lesson: without it fragment arrays demote to
// scratch). Only on compute-produced values (r12 lesson).
#define PIN(x) asm("" : "+v"(x))

__device__ __forceinline__ unsigned short f2bf(float f) {
  union { float f; unsigned u; } v; v.f = f;
  unsigned r = v.u + 0x7fffu + ((v.u >> 16) & 1u);   // RNE
  return (unsigned short)(r >> 16);
}

__device__ __forceinline__ unsigned pk2(float a, float b) {
  union { __hip_bfloat16 h[2]; unsigned u; } v;
  v.h[0] = __float2bfloat16(a);
  v.h[1] = __float2bfloat16(b);
  return v.u;
}

__device__ __forceinline__ void gload16(const void* g, void* l) {
  __builtin_amdgcn_global_load_lds(
      (const __attribute__((address_space(1))) unsigned int*)g,
      (__attribute__((address_space(3))) unsigned int*)l, 16, 0, 0);
}

__device__ __forceinline__ s16x8 frag1(unsigned d) {
  u32x4v v = {d, 0u, 0u, 0u};
  return __builtin_bit_cast(s16x8, v);
}

struct frag2 { s16x8 lo, hi; };

// 32x32 f32 acc -> bf16 -> relu -> two B-fragments (bit-exact relu-after-
// round via packed i16 max). 8 cvt_pk + 8 v_pk_max_i16, no cross-lane ops.
__device__ __forceinline__ frag2 cvt2(f32x16v a) {
  unsigned P[8];
#pragma unroll
  for (int q = 0; q < 8; ++q) {
    unsigned pk = pk2(a[2 * q], a[2 * q + 1]);
    asm("v_pk_max_i16 %0, %1, 0" : "=v"(P[q]) : "v"(pk));
  }
  u32x4v lo = {P[0], P[1], P[2], P[3]};
  u32x4v hh = {P[4], P[5], P[6], P[7]};
  frag2 r;
  r.lo = __builtin_bit_cast(s16x8, lo);
  r.hi = __builtin_bit_cast(s16x8, hh);
  return r;
}

// ---------------------------------------------------------------------------
// prep_wx: MERGED prep kernel (r16).
//  blocks 0..511:  w2,w3 fp32 [i][o] -> per-feature bf16 W^T [o][i] with
//    k-permutation (bit-exact, r7) + 16B-slot XOR (o&15).
//  blocks 512..767: x (B,F) -> xT (F,B) fp32 tiled transpose.
// ---------------------------------------------------------------------------
__global__ void prep_wx(const float* __restrict__ w2, const float* __restrict__ w3,
                        const float* __restrict__ x,
                        unsigned int* __restrict__ wTs, float* __restrict__ xT) {
  __shared__ __align__(16) float tile[128 * 130];   // w-path; x-path reuses
  const int blk = blockIdx.x;
  const int t = threadIdx.x;  // 256
  if (blk < 512) {
    const int m = blk;
    const float* src = (m < 256) ? (w2 + (size_t)m * 16384)
                                 : (w3 + (size_t)(m - 256) * 16384);
    for (int k = 0; k < 64; ++k) {
      int idx = k * 256 + t;
      int i = idx >> 7, o = idx & 127;
      tile[o * 130 + i] = src[idx];
    }
    __syncthreads();
    unsigned int* dst = wTs + (size_t)m * 8192;
    for (int k = 0; k < 32; ++k) {
      int idx = k * 256 + t;
      int o = idx >> 6, i2 = idx & 63;
      unsigned pk = (unsigned)f2bf(tile[o * 130 + 2 * i2]) |
                    ((unsigned)f2bf(tile[o * 130 + 2 * i2 + 1]) << 16);
      int w = i2 & 7;
      int i2p = (i2 & ~7) + ((w >> 1) & 1) * 4 + (w & 1) + (((w >> 2) & 1) << 1);
      dst[(o * 64) + (i2p ^ ((o & 15) << 2))] = pk;
    }
  } else {
    float (*xt)[65] = (float(*)[65])tile;
    const int bid = blk - 512;
    const int btile = bid & 63;
    const int ftile = bid >> 6;
    for (int k = 0; k < 16; ++k) {
      int idx = k * 256 + t;
      int r = idx >> 6, c = idx & 63;
      xt[r][c] = x[(size_t)(btile * 64 + r) * F_DIM + ftile * 64 + c];
    }
    __syncthreads();
    for (int k = 0; k < 16; ++k) {
      int idx = k * 256 + t;
      int fr = idx >> 6, br = idx & 63;
      xT[(size_t)(ftile * 64 + fr) * B_DIM + btile * 64 + br] = xt[br][fr];
    }
  }
}

// ---------------------------------------------------------------------------
// mlp_chain (r11 structure + r17 desync kick):
// 512 blocks = (feature f) x (batch half). 512 thr = 8 waves, (512,2).
// 1 block/CU resident (regs: 128 arch + ~64 acc = ~192 unified -> 2 waves/
// SIMD). r17: the two waves sharing a SIMD (wid and wid+4 under round-robin
// placement) start in phase and lockstep through identical MFMA/VALU/LDS
// phase patterns -> pipes serialize (~24000 cyc wall per iter vs ~3500 of
// issue). One-time ~3000-cycle s_sleep kick for waves 4-7 antiphases them
// so wave A's MFMA cluster fills wave B's stall windows (m114 co-schedule).
// ---------------------------------------------------------------------------
__global__ __launch_bounds__(512, 2) void mlp_chain(
    const float* __restrict__ xT, const float* __restrict__ w1,
    const float* __restrict__ b1, const float* __restrict__ b2,
    const float* __restrict__ b3, const float* __restrict__ w4,
    const float* __restrict__ b4, const unsigned int* __restrict__ wTs,
    float* __restrict__ xp) {
  __shared__ __align__(16) char Wb[2][128 * 256];   // 64 KiB swizzled W2^T,W3^T
  __shared__ __align__(16) float w4l[N_DIM];

  const int f    = blockIdx.x >> 1;
  const int half = blockIdx.x & 1;
  const int t    = threadIdx.x;
  const int lane = t & 63, wid = t >> 6;           // 8 waves
  const int c32 = lane & 31, hi = lane >> 5;

  // ---- stage W2[f], W3[f] (pre-swizzled bf16) -> LDS, linear gload ----
  {
    const char* s2 = (const char*)(wTs + (size_t)f * 8192);
    const char* s3 = (const char*)(wTs + (size_t)(256 + f) * 8192);
#pragma unroll
    for (int c = 0; c < 4; ++c) {
      int off = (wid * 4 + c) * 1024;
      gload16(s2 + off + lane * 16, &Wb[0][off]);
    }
#pragma unroll
    for (int c = 0; c < 4; ++c) {
      int off = (wid * 4 + c) * 1024;
      gload16(s3 + off + lane * 16, &Wb[1][off]);
    }
    if (t < 32) *(f32x4v*)&w4l[t * 4] = *(const f32x4v*)&w4[f * N_DIM + t * 4];
  }

  // ---- persistent rank-1/2 A-fragment dwords ----
  unsigned a1d[4], a2d[4], a3d[4];
#pragma unroll
  for (int it = 0; it < 4; ++it) {
    int i = it * 32 + c32;
    float w1v = w1[f * N_DIM + i], b1v = b1[f * N_DIM + i];
    float b2v = b2[f * N_DIM + i], b3v = b3[f * N_DIM + i];
    a1d[it] = hi ? 0u : pk2(w1v, b1v);
    a2d[it] = hi ? 0u : pk2(0.f, b2v);
    a3d[it] = hi ? 0u : pk2(0.f, b3v);
  }
  const float b4f = b4[f];
  const float* xcol = xT + (size_t)f * B_DIM + half * 2048;
  float* xprow = xp + (size_t)f * B_DIM + half * 2048;

  // hoisted per-lane swizzled W addresses
  const int wbase = c32 * 256 + (((lane & 15) ^ hi) << 4);
  int va[8];
#pragma unroll
  for (int m = 0; m < 8; ++m) { va[m] = wbase ^ (m << 5); PIN(va[m]); }
  const char* wb = &Wb[0][0];

  __syncthreads();   // the only block-wide barrier

  // ---- r17 desync kick: antiphase the SIMD-sharing wave pairs ----
  if (wid >= 4) {
#pragma unroll
    for (int s = 0; s < 7; ++s) __builtin_amdgcn_s_sleep(7);  // ~3100 cyc
  }

  const f32x16v zero = {0.f, 0.f, 0.f, 0.f, 0.f, 0.f, 0.f, 0.f,
                        0.f, 0.f, 0.f, 0.f, 0.f, 0.f, 0.f, 0.f};
  const f32x2v zz = {0.f, 0.f};

  float xvA = xcol[wid * 64 + c32];
  float xvB = xcol[wid * 64 + 32 + c32];
#pragma unroll 1
  for (int itb = 0; itb < 4; ++itb) {
    const int bb = itb * 512 + wid * 64;
    s16x8 BxA = frag1(hi ? 0u : pk2(xvA, 1.0f));
    s16x8 BxB = frag1(hi ? 0u : pk2(xvB, 1.0f));
    float xvA_n = (itb < 3) ? xcol[bb + 512 + c32] : 0.f;
    float xvB_n = (itb < 3) ? xcol[bb + 512 + 32 + c32] : 0.f;

    // ---- layer 1: H1 fragments via rank-2 outer MFMA ----
    s16x8 h1A[8], h1B[8];
#pragma unroll
    for (int it = 0; it < 4; ++it) {
      f32x16v hA = __builtin_amdgcn_mfma_f32_32x32x16_bf16(frag1(a1d[it]), BxA,
                                                           zero, 0, 0, 0);
      frag2 rA = cvt2(hA);
      h1A[2 * it] = rA.lo;  h1A[2 * it + 1] = rA.hi;
      PIN(h1A[2 * it]);  PIN(h1A[2 * it + 1]);
      f32x16v hB = __builtin_amdgcn_mfma_f32_32x32x16_bf16(frag1(a1d[it]), BxB,
                                                           zero, 0, 0, 0);
      frag2 rB = cvt2(hB);
      h1B[2 * it] = rB.lo;  h1B[2 * it + 1] = rB.hi;
      PIN(h1B[2 * it]);  PIN(h1B[2 * it + 1]);
    }

    // ---- layer 2: tile PAIRS, bias init shared across A/B ----
    s16x8 h2A[8], h2B[8];
#pragma unroll
    for (int ntp = 0; ntp < 2; ++ntp) {
      const int nt0 = 2 * ntp, nt1 = nt0 + 1;
      // bias tiles (x-independent: (0,b2) x (x,1) == b2 broadcast)
      f32x16v bi0 = __builtin_amdgcn_mfma_f32_32x32x16_bf16(frag1(a2d[nt0]), BxA,
                                                            zero, 0, 0, 0);
      f32x16v bi1 = __builtin_amdgcn_mfma_f32_32x32x16_bf16(frag1(a2d[nt1]), BxA,
                                                            zero, 0, 0, 0);
      f32x16v u0A, u0B, u1A, u1B;
      __builtin_amdgcn_s_setprio(1);
#pragma unroll
      for (int m = 0; m < 8; ++m) {
        s16x8 af0 = *(const s16x8*)(wb + va[m] + nt0 * 8192);
        s16x8 af1 = *(const s16x8*)(wb + va[m] + nt1 * 8192);
        u0A = __builtin_amdgcn_mfma_f32_32x32x16_bf16(af0, h1A[m],
                                                      m == 0 ? bi0 : u0A, 0, 0, 0);
        u0B = __builtin_amdgcn_mfma_f32_32x32x16_bf16(af0, h1B[m],
                                                      m == 0 ? bi0 : u0B, 0, 0, 0);
        u1A = __builtin_amdgcn_mfma_f32_32x32x16_bf16(af1, h1A[m],
                                                      m == 0 ? bi1 : u1A, 0, 0, 0);
        u1B = __builtin_amdgcn_mfma_f32_32x32x16_bf16(af1, h1B[m],
                                                      m == 0 ? bi1 : u1B, 0, 0, 0);
      }
      __builtin_amdgcn_s_setprio(0);
      frag2 r0A = cvt2(u0A);
      h2A[2 * nt0] = r0A.lo;  h2A[2 * nt0 + 1] = r0A.hi;
      PIN(h2A[2 * nt0]);  PIN(h2A[2 * nt0 + 1]);
      frag2 r0B = cvt2(u0B);
      h2B[2 * nt0] = r0B.lo;  h2B[2 * nt0 + 1] = r0B.hi;
      PIN(h2B[2 * nt0]);  PIN(h2B[2 * nt0 + 1]);
      frag2 r1A = cvt2(u1A);
      h2A[2 * nt1] = r1A.lo;  h2A[2 * nt1 + 1] = r1A.hi;
      PIN(h2A[2 * nt1]);  PIN(h2A[2 * nt1 + 1]);
      frag2 r1B = cvt2(u1B);
      h2B[2 * nt1] = r1B.lo;  h2B[2 * nt1 + 1] = r1B.hi;
      PIN(h2B[2 * nt1]);  PIN(h2B[2 * nt1 + 1]);
    }

    // ---- layer 3 (tile pairs, shared bias init) + layer 4 ----
    f32x2v pA0 = zz, pA1 = zz, pB0 = zz, pB1 = zz;
#pragma unroll
    for (int n3p = 0; n3p < 2; ++n3p) {
      const int n30 = 2 * n3p, n31 = n30 + 1;
      f32x16v ci0 = __builtin_amdgcn_mfma_f32_32x32x16_bf16(frag1(a3d[n30]), BxA,
                                                            zero, 0, 0, 0);
      f32x16v ci1 = __builtin_amdgcn_mfma_f32_32x32x16_bf16(frag1(a3d[n31]), BxA,
                                                            zero, 0, 0, 0);
      f32x16v v0A, v0B, v1A, v1B;
      __builtin_amdgcn_s_setprio(1);
#pragma unroll
      for (int k = 0; k < 8; ++k) {
        s16x8 af0 = *(const s16x8*)(wb + va[k] + 32768 + n30 * 8192);
        s16x8 af1 = *(const s16x8*)(wb + va[k] + 32768 + n31 * 8192);
        v0A = __builtin_amdgcn_mfma_f32_32x32x16_bf16(af0, h2A[k],
                                                      k == 0 ? ci0 : v0A, 0, 0, 0);
        v0B = __builtin_amdgcn_mfma_f32_32x32x16_bf16(af0, h2B[k],
                                                      k == 0 ? ci0 : v0B, 0, 0, 0);
        v1A = __builtin_amdgcn_mfma_f32_32x32x16_bf16(af1, h2A[k],
                                                      k == 0 ? ci1 : v1A, 0, 0, 0);
        v1B = __builtin_amdgcn_mfma_f32_32x32x16_bf16(af1, h2B[k],
                                                      k == 0 ? ci1 : v1B, 0, 0, 0);
      }
      __builtin_amdgcn_s_setprio(0);
      // layer 4: scalar relu + packed f32x2 fma (v_pk_fma_f32)
#pragma unroll
      for (int q = 0; q < 4; ++q) {
        f32x2v w01_0 = *(const f32x2v*)&w4l[n30 * 32 + q * 8 + hi * 4];
        f32x2v w23_0 = *(const f32x2v*)&w4l[n30 * 32 + q * 8 + hi * 4 + 2];
        f32x2v w01_1 = *(const f32x2v*)&w4l[n31 * 32 + q * 8 + hi * 4];
        f32x2v w23_1 = *(const f32x2v*)&w4l[n31 * 32 + q * 8 + hi * 4 + 2];
        f32x2v r;
        r[0] = fmaxf(v0A[4 * q + 0], 0.f); r[1] = fmaxf(v0A[4 * q + 1], 0.f);
        pA0 += r * w01_0;
        r[0] = fmaxf(v0A[4 * q + 2], 0.f); r[1] = fmaxf(v0A[4 * q + 3], 0.f);
        pA1 += r * w23_0;
        r[0] = fmaxf(v1A[4 * q + 0], 0.f); r[1] = fmaxf(v1A[4 * q + 1], 0.f);
        pA0 += r * w01_1;
        r[0] = fmaxf(v1A[4 * q + 2], 0.f); r[1] = fmaxf(v1A[4 * q + 3], 0.f);
        pA1 += r * w23_1;
        r[0] = fmaxf(v0B[4 * q + 0], 0.f); r[1] = fmaxf(v0B[4 * q + 1], 0.f);
        pB0 += r * w01_0;
        r[0] = fmaxf(v0B[4 * q + 2], 0.f); r[1] = fmaxf(v0B[4 * q + 3], 0.f);
        pB1 += r * w23_0;
        r[0] = fmaxf(v1B[4 * q + 0], 0.f); r[1] = fmaxf(v1B[4 * q + 1], 0.f);
        pB0 += r * w01_1;
        r[0] = fmaxf(v1B[4 * q + 2], 0.f); r[1] = fmaxf(v1B[4 * q + 3], 0.f);
        pB1 += r * w23_1;
      }
    }
    float pA = pA0[0] + pA0[1] + pA1[0] + pA1[1];
    float pB = pB0[0] + pB0[1] + pB1[0] + pB1[1];
    pA += __shfl_xor(pA, 32, 64);
    pB += __shfl_xor(pB, 32, 64);
    if (hi == 0) {
      xprow[bb + c32]      = pA + b4f;
      xprow[bb + 32 + c32] = pB + b4f;
    }
    xvA = xvA_n;
    xvB = xvB_n;
  }
}

// ---------------------------------------------------------------------------
// final_reduce: out[b] = lr_b + sum_f xp[f][b] * lr_w[f]
// ---------------------------------------------------------------------------
__global__ void final_reduce(const float* __restrict__ xp,
                             const float* __restrict__ lr_w,
                             const float* __restrict__ lr_b,
                             float* __restrict__ out) {
  __shared__ float lw[F_DIM];
  __shared__ float part[4][64];
  int t = threadIdx.x;   // 256
  if (t < F_DIM) lw[t] = lr_w[t];
  __syncthreads();
  int q = t >> 6, bl = t & 63;
  int b = blockIdx.x * 64 + bl;
  float acc = 0.f;
#pragma unroll 8
  for (int j = 0; j < 64; ++j) {
    int ff = q * 64 + j;
    acc += xp[(size_t)ff * B_DIM + b] * lw[ff];
  }
  part[q][bl] = acc;
  __syncthreads();
  if (q == 0)
    out[b] = part[0][bl] + part[1][bl] + part[2][bl] + part[3][bl] + lr_b[0];
}

// ---------------------------------------------------------------------------
extern "C" void kernel_launch(void* const* d_in, const int* in_sizes, int n_in,
                              void* d_out, int out_size, void* d_ws, size_t ws_size,
                              hipStream_t stream) {
  (void)in_sizes; (void)n_in; (void)out_size; (void)ws_size;
  const float* x    = (const float*)d_in[0];
  const float* w1   = (const float*)d_in[1];
  const float* b1   = (const float*)d_in[2];
  const float* w2   = (const float*)d_in[3];
  const float* b2   = (const float*)d_in[4];
  const float* w3   = (const float*)d_in[5];
  const float* b3   = (const float*)d_in[6];
  const float* w4   = (const float*)d_in[7];
  const float* b4   = (const float*)d_in[8];
  const float* lr_w = (const float*)d_in[9];
  const float* lr_b = (const float*)d_in[10];
  float* out = (float*)d_out;

  // ws layout: wTs 16 MiB | xT 4 MiB | xp 4 MiB
  char* ws = (char*)d_ws;
  unsigned int* wTs = (unsigned int*)ws;
  float* xT = (float*)(ws + (16u << 20));
  float* xp = (float*)(ws + (16u << 20) + (4u << 20));

  prep_wx<<<768, 256, 0, stream>>>(w2, w3, x, wTs, xT);
  mlp_chain<<<512, 512, 0, stream>>>(xT, w1, b1, b2, b3, w4, b4, wTs, xp);
  final_reduce<<<64, 256, 0, stream>>>(xp, lr_w, lr_b, out);
}

// Round 18
// 85.174 us; speedup vs baseline: 1.0779x; 1.0779x over previous
//
#include <hip/hip_runtime.h>
#include <hip/hip_bf16.h>

#define F_DIM 256
#define N_DIM 128
#define B_DIM 4096

typedef float f32x2v __attribute__((ext_vector_type(2)));
typedef float f32x4v __attribute__((ext_vector_type(4)));
typedef float f32x16v __attribute__((ext_vector_type(16)));
typedef short s16x8 __attribute__((ext_vector_type(8)));
typedef unsigned int u32x4v __attribute__((ext_vector_type(4)));

// zero-cost VGPR pin (r7 lesson: without it fragment arrays demote to
// scratch). Only on compute-produced values (r12 lesson).
#define PIN(x) asm("" : "+v"(x))

__device__ __forceinline__ unsigned short f2bf(float f) {
  union { float f; unsigned u; } v; v.f = f;
  unsigned r = v.u + 0x7fffu + ((v.u >> 16) & 1u);   // RNE
  return (unsigned short)(r >> 16);
}

__device__ __forceinline__ unsigned pk2(float a, float b) {
  union { __hip_bfloat16 h[2]; unsigned u; } v;
  v.h[0] = __float2bfloat16(a);
  v.h[1] = __float2bfloat16(b);
  return v.u;
}

__device__ __forceinline__ void gload16(const void* g, void* l) {
  __builtin_amdgcn_global_load_lds(
      (const __attribute__((address_space(1))) unsigned int*)g,
      (__attribute__((address_space(3))) unsigned int*)l, 16, 0, 0);
}

__device__ __forceinline__ s16x8 frag1(unsigned d) {
  u32x4v v = {d, 0u, 0u, 0u};
  return __builtin_bit_cast(s16x8, v);
}

struct frag2 { s16x8 lo, hi; };

// 32x32 f32 acc -> bf16 -> relu -> two B-fragments (bit-exact relu-after-
// round via packed i16 max). 8 cvt_pk + 8 v_pk_max_i16, no cross-lane ops.
__device__ __forceinline__ frag2 cvt2(f32x16v a) {
  unsigned P[8];
#pragma unroll
  for (int q = 0; q < 8; ++q) {
    unsigned pk = pk2(a[2 * q], a[2 * q + 1]);
    asm("v_pk_max_i16 %0, %1, 0" : "=v"(P[q]) : "v"(pk));
  }
  u32x4v lo = {P[0], P[1], P[2], P[3]};
  u32x4v hh = {P[4], P[5], P[6], P[7]};
  frag2 r;
  r.lo = __builtin_bit_cast(s16x8, lo);
  r.hi = __builtin_bit_cast(s16x8, hh);
  return r;
}

// ---------------------------------------------------------------------------
// prep_wx: MERGED prep kernel (r16).
//  blocks 0..511:  w2,w3 fp32 [i][o] -> per-feature bf16 W^T [o][i] with
//    k-permutation (bit-exact, r7) + 16B-slot XOR (o&15).
//  blocks 512..767: x (B,F) -> xT (F,B) fp32 tiled transpose.
// ---------------------------------------------------------------------------
__global__ void prep_wx(const float* __restrict__ w2, const float* __restrict__ w3,
                        const float* __restrict__ x,
                        unsigned int* __restrict__ wTs, float* __restrict__ xT) {
  __shared__ __align__(16) float tile[128 * 130];   // w-path; x-path reuses
  const int blk = blockIdx.x;
  const int t = threadIdx.x;  // 256
  if (blk < 512) {
    const int m = blk;
    const float* src = (m < 256) ? (w2 + (size_t)m * 16384)
                                 : (w3 + (size_t)(m - 256) * 16384);
    for (int k = 0; k < 64; ++k) {
      int idx = k * 256 + t;
      int i = idx >> 7, o = idx & 127;
      tile[o * 130 + i] = src[idx];
    }
    __syncthreads();
    unsigned int* dst = wTs + (size_t)m * 8192;
    for (int k = 0; k < 32; ++k) {
      int idx = k * 256 + t;
      int o = idx >> 6, i2 = idx & 63;
      unsigned pk = (unsigned)f2bf(tile[o * 130 + 2 * i2]) |
                    ((unsigned)f2bf(tile[o * 130 + 2 * i2 + 1]) << 16);
      int w = i2 & 7;
      int i2p = (i2 & ~7) + ((w >> 1) & 1) * 4 + (w & 1) + (((w >> 2) & 1) << 1);
      dst[(o * 64) + (i2p ^ ((o & 15) << 2))] = pk;
    }
  } else {
    float (*xt)[65] = (float(*)[65])tile;
    const int bid = blk - 512;
    const int btile = bid & 63;
    const int ftile = bid >> 6;
    for (int k = 0; k < 16; ++k) {
      int idx = k * 256 + t;
      int r = idx >> 6, c = idx & 63;
      xt[r][c] = x[(size_t)(btile * 64 + r) * F_DIM + ftile * 64 + c];
    }
    __syncthreads();
    for (int k = 0; k < 16; ++k) {
      int idx = k * 256 + t;
      int fr = idx >> 6, br = idx & 63;
      xT[(size_t)(ftile * 64 + fr) * B_DIM + btile * 64 + br] = xt[br][fr];
    }
  }
}

// ---------------------------------------------------------------------------
// mlp_chain (r18: single-round grid):
// 256 blocks = one per feature, 8 iterations x 512 batch cols. 512 thr =
// 8 waves, (512,2) -> VGPR cap 128. Exactly 1 block/CU resident and grid ==
// CU count -> ONE dispatch round, ONE W-staging phase (r16's grid 512 paid
// two sequential rounds each with stage+ramp). Structure is the r11 local
// optimum: dual batch sets (A,B), tile-pair MFMA chains (4 independent),
// bias-init MFMAs shared across A/B, hoisted swizzled LDS addrs,
// relu-after-pack cvt2, packed f32x2 L4, setprio on MFMA clusters, no
// barriers in the loop. 2 waves/SIMD is a characterized triple-wall (LDS
// 64KB weights x 192-reg waves x block granularity); r12-r17 falsified all
// escape routes (prefetch, SGB, lean, wreg-exchange, desync).
// ---------------------------------------------------------------------------
__global__ __launch_bounds__(512, 2) void mlp_chain(
    const float* __restrict__ xT, const float* __restrict__ w1,
    const float* __restrict__ b1, const float* __restrict__ b2,
    const float* __restrict__ b3, const float* __restrict__ w4,
    const float* __restrict__ b4, const unsigned int* __restrict__ wTs,
    float* __restrict__ xp) {
  __shared__ __align__(16) char Wb[2][128 * 256];   // 64 KiB swizzled W2^T,W3^T
  __shared__ __align__(16) float w4l[N_DIM];

  const int f    = blockIdx.x;
  const int t    = threadIdx.x;
  const int lane = t & 63, wid = t >> 6;           // 8 waves
  const int c32 = lane & 31, hi = lane >> 5;

  // ---- stage W2[f], W3[f] (pre-swizzled bf16) -> LDS, linear gload ----
  {
    const char* s2 = (const char*)(wTs + (size_t)f * 8192);
    const char* s3 = (const char*)(wTs + (size_t)(256 + f) * 8192);
#pragma unroll
    for (int c = 0; c < 4; ++c) {
      int off = (wid * 4 + c) * 1024;
      gload16(s2 + off + lane * 16, &Wb[0][off]);
    }
#pragma unroll
    for (int c = 0; c < 4; ++c) {
      int off = (wid * 4 + c) * 1024;
      gload16(s3 + off + lane * 16, &Wb[1][off]);
    }
    if (t < 32) *(f32x4v*)&w4l[t * 4] = *(const f32x4v*)&w4[f * N_DIM + t * 4];
  }

  // ---- persistent rank-1/2 A-fragment dwords ----
  unsigned a1d[4], a2d[4], a3d[4];
#pragma unroll
  for (int it = 0; it < 4; ++it) {
    int i = it * 32 + c32;
    float w1v = w1[f * N_DIM + i], b1v = b1[f * N_DIM + i];
    float b2v = b2[f * N_DIM + i], b3v = b3[f * N_DIM + i];
    a1d[it] = hi ? 0u : pk2(w1v, b1v);
    a2d[it] = hi ? 0u : pk2(0.f, b2v);
    a3d[it] = hi ? 0u : pk2(0.f, b3v);
  }
  const float b4f = b4[f];
  const float* xcol = xT + (size_t)f * B_DIM;
  float* xprow = xp + (size_t)f * B_DIM;

  // hoisted per-lane swizzled W addresses
  const int wbase = c32 * 256 + (((lane & 15) ^ hi) << 4);
  int va[8];
#pragma unroll
  for (int m = 0; m < 8; ++m) { va[m] = wbase ^ (m << 5); PIN(va[m]); }
  const char* wb = &Wb[0][0];

  __syncthreads();   // the only block-wide barrier

  const f32x16v zero = {0.f, 0.f, 0.f, 0.f, 0.f, 0.f, 0.f, 0.f,
                        0.f, 0.f, 0.f, 0.f, 0.f, 0.f, 0.f, 0.f};
  const f32x2v zz = {0.f, 0.f};

  float xvA = xcol[wid * 64 + c32];
  float xvB = xcol[wid * 64 + 32 + c32];
#pragma unroll 1
  for (int itb = 0; itb < 8; ++itb) {
    const int bb = itb * 512 + wid * 64;
    s16x8 BxA = frag1(hi ? 0u : pk2(xvA, 1.0f));
    s16x8 BxB = frag1(hi ? 0u : pk2(xvB, 1.0f));
    float xvA_n = (itb < 7) ? xcol[bb + 512 + c32] : 0.f;
    float xvB_n = (itb < 7) ? xcol[bb + 512 + 32 + c32] : 0.f;

    // ---- layer 1: H1 fragments via rank-2 outer MFMA ----
    s16x8 h1A[8], h1B[8];
#pragma unroll
    for (int it = 0; it < 4; ++it) {
      f32x16v hA = __builtin_amdgcn_mfma_f32_32x32x16_bf16(frag1(a1d[it]), BxA,
                                                           zero, 0, 0, 0);
      frag2 rA = cvt2(hA);
      h1A[2 * it] = rA.lo;  h1A[2 * it + 1] = rA.hi;
      PIN(h1A[2 * it]);  PIN(h1A[2 * it + 1]);
      f32x16v hB = __builtin_amdgcn_mfma_f32_32x32x16_bf16(frag1(a1d[it]), BxB,
                                                           zero, 0, 0, 0);
      frag2 rB = cvt2(hB);
      h1B[2 * it] = rB.lo;  h1B[2 * it + 1] = rB.hi;
      PIN(h1B[2 * it]);  PIN(h1B[2 * it + 1]);
    }

    // ---- layer 2: tile PAIRS, bias init shared across A/B ----
    s16x8 h2A[8], h2B[8];
#pragma unroll
    for (int ntp = 0; ntp < 2; ++ntp) {
      const int nt0 = 2 * ntp, nt1 = nt0 + 1;
      // bias tiles (x-independent: (0,b2) x (x,1) == b2 broadcast)
      f32x16v bi0 = __builtin_amdgcn_mfma_f32_32x32x16_bf16(frag1(a2d[nt0]), BxA,
                                                            zero, 0, 0, 0);
      f32x16v bi1 = __builtin_amdgcn_mfma_f32_32x32x16_bf16(frag1(a2d[nt1]), BxA,
                                                            zero, 0, 0, 0);
      f32x16v u0A, u0B, u1A, u1B;
      __builtin_amdgcn_s_setprio(1);
#pragma unroll
      for (int m = 0; m < 8; ++m) {
        s16x8 af0 = *(const s16x8*)(wb + va[m] + nt0 * 8192);
        s16x8 af1 = *(const s16x8*)(wb + va[m] + nt1 * 8192);
        u0A = __builtin_amdgcn_mfma_f32_32x32x16_bf16(af0, h1A[m],
                                                      m == 0 ? bi0 : u0A, 0, 0, 0);
        u0B = __builtin_amdgcn_mfma_f32_32x32x16_bf16(af0, h1B[m],
                                                      m == 0 ? bi0 : u0B, 0, 0, 0);
        u1A = __builtin_amdgcn_mfma_f32_32x32x16_bf16(af1, h1A[m],
                                                      m == 0 ? bi1 : u1A, 0, 0, 0);
        u1B = __builtin_amdgcn_mfma_f32_32x32x16_bf16(af1, h1B[m],
                                                      m == 0 ? bi1 : u1B, 0, 0, 0);
      }
      __builtin_amdgcn_s_setprio(0);
      frag2 r0A = cvt2(u0A);
      h2A[2 * nt0] = r0A.lo;  h2A[2 * nt0 + 1] = r0A.hi;
      PIN(h2A[2 * nt0]);  PIN(h2A[2 * nt0 + 1]);
      frag2 r0B = cvt2(u0B);
      h2B[2 * nt0] = r0B.lo;  h2B[2 * nt0 + 1] = r0B.hi;
      PIN(h2B[2 * nt0]);  PIN(h2B[2 * nt0 + 1]);
      frag2 r1A = cvt2(u1A);
      h2A[2 * nt1] = r1A.lo;  h2A[2 * nt1 + 1] = r1A.hi;
      PIN(h2A[2 * nt1]);  PIN(h2A[2 * nt1 + 1]);
      frag2 r1B = cvt2(u1B);
      h2B[2 * nt1] = r1B.lo;  h2B[2 * nt1 + 1] = r1B.hi;
      PIN(h2B[2 * nt1]);  PIN(h2B[2 * nt1 + 1]);
    }

    // ---- layer 3 (tile pairs, shared bias init) + layer 4 ----
    f32x2v pA0 = zz, pA1 = zz, pB0 = zz, pB1 = zz;
#pragma unroll
    for (int n3p = 0; n3p < 2; ++n3p) {
      const int n30 = 2 * n3p, n31 = n30 + 1;
      f32x16v ci0 = __builtin_amdgcn_mfma_f32_32x32x16_bf16(frag1(a3d[n30]), BxA,
                                                            zero, 0, 0, 0);
      f32x16v ci1 = __builtin_amdgcn_mfma_f32_32x32x16_bf16(frag1(a3d[n31]), BxA,
                                                            zero, 0, 0, 0);
      f32x16v v0A, v0B, v1A, v1B;
      __builtin_amdgcn_s_setprio(1);
#pragma unroll
      for (int k = 0; k < 8; ++k) {
        s16x8 af0 = *(const s16x8*)(wb + va[k] + 32768 + n30 * 8192);
        s16x8 af1 = *(const s16x8*)(wb + va[k] + 32768 + n31 * 8192);
        v0A = __builtin_amdgcn_mfma_f32_32x32x16_bf16(af0, h2A[k],
                                                      k == 0 ? ci0 : v0A, 0, 0, 0);
        v0B = __builtin_amdgcn_mfma_f32_32x32x16_bf16(af0, h2B[k],
                                                      k == 0 ? ci0 : v0B, 0, 0, 0);
        v1A = __builtin_amdgcn_mfma_f32_32x32x16_bf16(af1, h2A[k],
                                                      k == 0 ? ci1 : v1A, 0, 0, 0);
        v1B = __builtin_amdgcn_mfma_f32_32x32x16_bf16(af1, h2B[k],
                                                      k == 0 ? ci1 : v1B, 0, 0, 0);
      }
      __builtin_amdgcn_s_setprio(0);
      // layer 4: scalar relu + packed f32x2 fma (v_pk_fma_f32)
#pragma unroll
      for (int q = 0; q < 4; ++q) {
        f32x2v w01_0 = *(const f32x2v*)&w4l[n30 * 32 + q * 8 + hi * 4];
        f32x2v w23_0 = *(const f32x2v*)&w4l[n30 * 32 + q * 8 + hi * 4 + 2];
        f32x2v w01_1 = *(const f32x2v*)&w4l[n31 * 32 + q * 8 + hi * 4];
        f32x2v w23_1 = *(const f32x2v*)&w4l[n31 * 32 + q * 8 + hi * 4 + 2];
        f32x2v r;
        r[0] = fmaxf(v0A[4 * q + 0], 0.f); r[1] = fmaxf(v0A[4 * q + 1], 0.f);
        pA0 += r * w01_0;
        r[0] = fmaxf(v0A[4 * q + 2], 0.f); r[1] = fmaxf(v0A[4 * q + 3], 0.f);
        pA1 += r * w23_0;
        r[0] = fmaxf(v1A[4 * q + 0], 0.f); r[1] = fmaxf(v1A[4 * q + 1], 0.f);
        pA0 += r * w01_1;
        r[0] = fmaxf(v1A[4 * q + 2], 0.f); r[1] = fmaxf(v1A[4 * q + 3], 0.f);
        pA1 += r * w23_1;
        r[0] = fmaxf(v0B[4 * q + 0], 0.f); r[1] = fmaxf(v0B[4 * q + 1], 0.f);
        pB0 += r * w01_0;
        r[0] = fmaxf(v0B[4 * q + 2], 0.f); r[1] = fmaxf(v0B[4 * q + 3], 0.f);
        pB1 += r * w23_0;
        r[0] = fmaxf(v1B[4 * q + 0], 0.f); r[1] = fmaxf(v1B[4 * q + 1], 0.f);
        pB0 += r * w01_1;
        r[0] = fmaxf(v1B[4 * q + 2], 0.f); r[1] = fmaxf(v1B[4 * q + 3], 0.f);
        pB1 += r * w23_1;
      }
    }
    float pA = pA0[0] + pA0[1] + pA1[0] + pA1[1];
    float pB = pB0[0] + pB0[1] + pB1[0] + pB1[1];
    pA += __shfl_xor(pA, 32, 64);
    pB += __shfl_xor(pB, 32, 64);
    if (hi == 0) {
      xprow[bb + c32]      = pA + b4f;
      xprow[bb + 32 + c32] = pB + b4f;
    }
    xvA = xvA_n;
    xvB = xvB_n;
  }
}

// ---------------------------------------------------------------------------
// final_reduce: out[b] = lr_b + sum_f xp[f][b] * lr_w[f]
// ---------------------------------------------------------------------------
__global__ void final_reduce(const float* __restrict__ xp,
                             const float* __restrict__ lr_w,
                             const float* __restrict__ lr_b,
                             float* __restrict__ out) {
  __shared__ float lw[F_DIM];
  __shared__ float part[4][64];
  int t = threadIdx.x;   // 256
  if (t < F_DIM) lw[t] = lr_w[t];
  __syncthreads();
  int q = t >> 6, bl = t & 63;
  int b = blockIdx.x * 64 + bl;
  float acc = 0.f;
#pragma unroll 8
  for (int j = 0; j < 64; ++j) {
    int ff = q * 64 + j;
    acc += xp[(size_t)ff * B_DIM + b] * lw[ff];
  }
  part[q][bl] = acc;
  __syncthreads();
  if (q == 0)
    out[b] = part[0][bl] + part[1][bl] + part[2][bl] + part[3][bl] + lr_b[0];
}

// ---------------------------------------------------------------------------
extern "C" void kernel_launch(void* const* d_in, const int* in_sizes, int n_in,
                              void* d_out, int out_size, void* d_ws, size_t ws_size,
                              hipStream_t stream) {
  (void)in_sizes; (void)n_in; (void)out_size; (void)ws_size;
  const float* x    = (const float*)d_in[0];
  const float* w1   = (const float*)d_in[1];
  const float* b1   = (const float*)d_in[2];
  const float* w2   = (const float*)d_in[3];
  const float* b2   = (const float*)d_in[4];
  const float* w3   = (const float*)d_in[5];
  const float* b3   = (const float*)d_in[6];
  const float* w4   = (const float*)d_in[7];
  const float* b4   = (const float*)d_in[8];
  const float* lr_w = (const float*)d_in[9];
  const float* lr_b = (const float*)d_in[10];
  float* out = (float*)d_out;

  // ws layout: wTs 16 MiB | xT 4 MiB | xp 4 MiB
  char* ws = (char*)d_ws;
  unsigned int* wTs = (unsigned int*)ws;
  float* xT = (float*)(ws + (16u << 20));
  float* xp = (float*)(ws + (16u << 20) + (4u << 20));

  prep_wx<<<768, 256, 0, stream>>>(w2, w3, x, wTs, xT);
  mlp_chain<<<256, 512, 0, stream>>>(xT, w1, b1, b2, b3, w4, b4, wTs, xp);
  final_reduce<<<64, 256, 0, stream>>>(xp, lr_w, lr_b, out);
}